// Round 7
// baseline (324.901 us; speedup 1.0000x reference)
//
#include <hip/hip_runtime.h>

#define M_DIM 8192
#define N_DIM 4096
#define K_DIM 4096

typedef __bf16 bf16x8 __attribute__((ext_vector_type(8)));
typedef float f32x4 __attribute__((ext_vector_type(4)));

// bf16 round-to-nearest-even from fp32 (no NaN in this problem)
__device__ __forceinline__ unsigned short f2bf(float f) {
    unsigned u = __float_as_uint(f);
    u += 0x7FFFu + ((u >> 16) & 1u);
    return (unsigned short)(u >> 16);
}

// Bit-exact replica of reference _cast_e4m3 (round-half-even, subnormals, sat 448)
__device__ __forceinline__ float cast_e4m3(float v) {
    float a = fminf(fabsf(v), 448.0f);
    float am = fmaxf(a, 0x1p-9f);
    int e = (int)((__float_as_uint(am) >> 23) & 0xFFu) - 127;   // floor(log2(am)), exact
    e = (e < -6) ? -6 : e;
    float step = __uint_as_float((unsigned)(e - 3 + 127) << 23); // 2^(e-3)
    float q = rintf(a / step) * step;                            // a/step exact, RNE tie
    q = fminf(q, 448.0f);
    return (v < 0.0f) ? -q : q;
}

// x: per-row 1x128 blocks. One 32-lane group per block, 4 floats/lane.
__global__ __launch_bounds__(256) void quant_x(const float* __restrict__ X,
                                               unsigned short* __restrict__ Xq) {
    const int g = threadIdx.x >> 5;
    const int l = threadIdx.x & 31;
    const long rb = (long)blockIdx.x * 8 + g;
    const int row = (int)(rb >> 5);
    const int kb = (int)(rb & 31);
    const size_t base = (size_t)row * K_DIM + kb * 128 + l * 4;
    const float4 v = *(const float4*)&X[base];
    float amax = fmaxf(fmaxf(fabsf(v.x), fabsf(v.y)), fmaxf(fabsf(v.z), fabsf(v.w)));
    #pragma unroll
    for (int m = 16; m >= 1; m >>= 1)
        amax = fmaxf(amax, __shfl_xor(amax, m));
    const float scale = fmaxf(amax, 1e-12f) / 448.0f;
    ushort4 o;
    o.x = f2bf(cast_e4m3(v.x / scale) * scale);
    o.y = f2bf(cast_e4m3(v.y / scale) * scale);
    o.z = f2bf(cast_e4m3(v.z / scale) * scale);
    o.w = f2bf(cast_e4m3(v.w / scale) * scale);
    *(ushort4*)&Xq[base] = o;
}

// w: 128x128 tiles. One 256-thread block per tile; values held in registers.
__global__ __launch_bounds__(256) void quant_w(const float* __restrict__ W,
                                               unsigned short* __restrict__ Wq) {
    const int tile = blockIdx.x;
    const int tr = tile >> 5;
    const int tc = tile & 31;
    const int t = threadIdx.x;
    const int c4 = (t & 31) * 4;
    const float* base = W + (size_t)(tr * 128) * K_DIM + tc * 128;

    float4 v[16];
    float amax = 0.0f;
    #pragma unroll
    for (int p = 0; p < 16; ++p) {
        const int r = p * 8 + (t >> 5);
        v[p] = *(const float4*)&base[(size_t)r * K_DIM + c4];
        amax = fmaxf(amax, fmaxf(fmaxf(fabsf(v[p].x), fabsf(v[p].y)),
                                 fmaxf(fabsf(v[p].z), fabsf(v[p].w))));
    }
    #pragma unroll
    for (int m = 32; m >= 1; m >>= 1)
        amax = fmaxf(amax, __shfl_xor(amax, m));
    __shared__ float red[4];
    if ((t & 63) == 0) red[t >> 6] = amax;
    __syncthreads();
    const float am4 = fmaxf(fmaxf(red[0], red[1]), fmaxf(red[2], red[3]));
    const float scale = fmaxf(am4, 1e-12f) / 448.0f;

    unsigned short* out = Wq + (size_t)(tr * 128) * K_DIM + tc * 128;
    #pragma unroll
    for (int p = 0; p < 16; ++p) {
        const int r = p * 8 + (t >> 5);
        ushort4 o;
        o.x = f2bf(cast_e4m3(v[p].x / scale) * scale);
        o.y = f2bf(cast_e4m3(v[p].y / scale) * scale);
        o.z = f2bf(cast_e4m3(v[p].z / scale) * scale);
        o.w = f2bf(cast_e4m3(v[p].w / scale) * scale);
        *(ushort4*)&out[(size_t)r * K_DIM + c4] = o;
    }
}

#define GLOAD16(g, l)                                                          \
    __builtin_amdgcn_global_load_lds(                                          \
        (const __attribute__((address_space(1))) void*)(g),                    \
        (__attribute__((address_space(3))) void*)(l), 16, 0, 0)

// ============ 256x256 GEMM, BK=64, 8 waves, read-one-phase-ahead ============
// LDS element bases: AE=0, AO=16384, BE=32768, BO=49152 (x2B = 128KiB).
// Even tile -> E bufs, odd -> O.  Quadrants: Q1=MMA(a0,0,0,b0cur),
// Q2=MMA(a0,0,1,b1), Q3=MMA(a1,1,1,b1), Q4=MMA(a1,1,0,b0cur).
// READS are issued ONE PHASE before use (counted lgkm waits):
//   P1: b1(t)[4]      wait lgkm(4)  (drains a0,b0 issued at P4 prev)
//   P2: a1(t)[8]      wait lgkm(8)  (drains b1)
//   P3: --            wait lgkm(0)  (drains a1)
//   P4: a0,b0nxt(t+1)[12]  no wait  (drained at next P1's lgkm(4))
// STAGES: P1: A(t+1) both halves; P3: B0(t+2); P4: B1(t+2).
// Single vmcnt(2) per tile at P3 (pre-trailing-barrier): drains B1(t+1)
// [P4(t-1)] + A(t+1) [P1(t)], all issued >=2 phases (~2300cy) before the
// wait -> no HBM-latency stall; leaves B0(t+2) in flight.  P4's reads of
// buf(t+1) issue after P3's trailing barrier => after ALL waves' vmcnt
// drains (cross-wave safety).  Stage-over-read: B(t)-buf reads drain at
// P2's lgkm (pre-P2-barrier) -> stage B(t+2) at P3/P4 >=1 barrier later;
// A(t)-buf reads drain at P3's lgkm -> stage A(t+2) at P1(t+1), >=2
// barriers later.  Lead barriers are redundant under this ledger: 4
// barriers/tile.  Zero-cost asm fences pin memory-op issue order per
// phase so the counted lgkm/vmcnt values stay exact.
// Swizzle (R5-verified, SQ_LDS_BANK_CONFLICT==0): LDS[row][c] holds
// element (row, c ^ ((row&7)<<3)); linear LDS dest + inverse-permuted
// global source col (rows 0-7 of each 8-lane b128 group cover all 8
// bank-quads).  kt clamped to 63: tail stages write dead regions.

#define BARRIER() __builtin_amdgcn_s_barrier()
#define FENCE()  asm volatile("" ::: "memory")
#define LGKM(n)  asm volatile("s_waitcnt lgkmcnt(" #n ")" ::: "memory")
#define VMC(n)   asm volatile("s_waitcnt vmcnt(" #n ")" ::: "memory")
#define PRIO1()  __builtin_amdgcn_s_setprio(1)
#define PRIO0()  __builtin_amdgcn_s_setprio(0)

#define STAGE(G, grow0, kt, ebase, ht) do {                                    \
    const int _kt = (kt) > 63 ? 63 : (kt);                                     \
    const unsigned short* _s0 = (G) +                                          \
        (size_t)((grow0) + (ht) * 128 + w * 8 + sr) * K_DIM + _kt * 64 + src_col; \
    const unsigned short* _s1 = _s0 + (size_t)64 * K_DIM;                      \
    char* _lb = (char*)lds + (ebase) * 2 + ((ht) * 128 + w * 8) * 128;         \
    GLOAD16(_s0, _lb);                                                         \
    GLOAD16(_s1, _lb + 8192);                                                  \
} while (0)

#define LDA(dst, mh, ebase) do {                                               \
    _Pragma("unroll") for (int _m = 0; _m < 4; ++_m) {                         \
        const int _row = wm * 128 + (mh) * 64 + _m * 16 + lr;                  \
        dst[_m][0] = *(const bf16x8*)&lds[(ebase) + _row * 64 + ((0  + hk) ^ rsw)]; \
        dst[_m][1] = *(const bf16x8*)&lds[(ebase) + _row * 64 + ((32 + hk) ^ rsw)]; \
    }                                                                          \
} while (0)

#define LDB(dst, nh, ebase) do {                                               \
    _Pragma("unroll") for (int _n = 0; _n < 2; ++_n) {                         \
        const int _row = wn * 64 + (nh) * 32 + _n * 16 + lr;                   \
        dst[_n][0] = *(const bf16x8*)&lds[(ebase) + _row * 64 + ((0  + hk) ^ rsw)]; \
        dst[_n][1] = *(const bf16x8*)&lds[(ebase) + _row * 64 + ((32 + hk) ^ rsw)]; \
    }                                                                          \
} while (0)

#define MMA(aA, mh, nh, bB) do {                                               \
    _Pragma("unroll") for (int _m = 0; _m < 4; ++_m)                           \
    _Pragma("unroll") for (int _n = 0; _n < 2; ++_n)                           \
    _Pragma("unroll") for (int _k = 0; _k < 2; ++_k)                           \
        acc[(mh) * 4 + _m][(nh) * 2 + _n] =                                    \
            __builtin_amdgcn_mfma_f32_16x16x32_bf16(                           \
                aA[_m][_k], bB[_n][_k], acc[(mh) * 4 + _m][(nh) * 2 + _n], 0, 0, 0); \
} while (0)

#define AE 0
#define AO 16384
#define BE 32768
#define BO 49152

__global__ __launch_bounds__(512, 2) void gemm256(const unsigned short* __restrict__ A,
                                                  const unsigned short* __restrict__ B,
                                                  const float* __restrict__ bias,
                                                  float* __restrict__ C) {
    __shared__ __align__(16) unsigned short lds[65536];   // 128 KiB

    const int t = threadIdx.x;
    const int lane = t & 63;
    const int w = t >> 6;                 // 0..7
    const int wm = w >> 2, wn = w & 3;    // 2M x 4N wave grid

    int bid = blockIdx.x;
    bid = (bid & 7) * 64 + (bid >> 3);    // 512 blocks, %8==0 -> bijective
    const int bm = bid >> 4, bn = bid & 15;
    const size_t brow = (size_t)bm * 256, bcol = (size_t)bn * 256;

    // stage-side lane constants: row-in-8 = lane>>3; inverse-swizzled source col
    const int sr = lane >> 3;
    const int src_col = (((lane & 7) ^ ((lane >> 3) & 7)) << 3);
    // read-side lane constants
    const int lr = lane & 15;
    const int hk = (lane >> 4) * 8;
    const int rsw = (lane & 7) << 3;      // col ^= (row&7)<<3, row&7 == lane&7

    f32x4 acc[8][4] = {};
    bf16x8 a0[4][2], a1[4][2], b0e[2][2], b0o[2][2], b1[2][2];

    // prologue: stage A(0),B(0) -> E bufs, B(1) -> BO (12 loads);
    // drain tile 0 (leave B(1) in flight); then issue the "P4(-1)" reads.
    STAGE(A, brow, 0, AE, 0); STAGE(A, brow, 0, AE, 1);
    STAGE(B, bcol, 0, BE, 0); STAGE(B, bcol, 0, BE, 1);
    STAGE(B, bcol, 1, BO, 0); STAGE(B, bcol, 1, BO, 1);
    VMC(4); BARRIER(); FENCE();
    LDA(a0, 0, AE); LDB(b0e, 0, BE);      // 12 ds_reads, drained at P1's lgkm(4)
    FENCE();

    for (int u = 0; u < 64; u += 2) {
        // ---- even tile u (E bufs, b0e) ----
        // P1
        LDB(b1, 1, BE);
        STAGE(A, brow, u + 1, AO, 0); STAGE(A, brow, u + 1, AO, 1);
        LGKM(4);
        PRIO1(); MMA(a0, 0, 0, b0e); PRIO0();
        BARRIER(); FENCE();
        // P2
        LDA(a1, 1, AE);
        LGKM(8);
        PRIO1(); MMA(a0, 0, 1, b1); PRIO0();
        BARRIER(); FENCE();
        // P3
        STAGE(B, bcol, u + 2, BE, 0);
        LGKM(0);
        PRIO1(); MMA(a1, 1, 1, b1); PRIO0();
        VMC(2);
        BARRIER(); FENCE();
        // P4
        LDA(a0, 0, AO); LDB(b0o, 0, BO);
        STAGE(B, bcol, u + 2, BE, 1);
        PRIO1(); MMA(a1, 1, 0, b0e); PRIO0();
        BARRIER(); FENCE();

        // ---- odd tile u+1 (O bufs, b0o) ----
        // P1
        LDB(b1, 1, BO);
        STAGE(A, brow, u + 2, AE, 0); STAGE(A, brow, u + 2, AE, 1);
        LGKM(4);
        PRIO1(); MMA(a0, 0, 0, b0o); PRIO0();
        BARRIER(); FENCE();
        // P2
        LDA(a1, 1, AO);
        LGKM(8);
        PRIO1(); MMA(a0, 0, 1, b1); PRIO0();
        BARRIER(); FENCE();
        // P3
        STAGE(B, bcol, u + 3, BO, 0);
        LGKM(0);
        PRIO1(); MMA(a1, 1, 1, b1); PRIO0();
        VMC(2);
        BARRIER(); FENCE();
        // P4
        LDA(a0, 0, AE); LDB(b0e, 0, BE);
        STAGE(B, bcol, u + 3, BO, 1);
        PRIO1(); MMA(a1, 1, 0, b0o); PRIO0();
        BARRIER(); FENCE();
    }

    LGKM(0); VMC(0);   // drain tail garbage reads + dead stages
    BARRIER();

    // C write: acc[i][j] -> row = wm*128 + i*16 + (lane>>4)*4 + jj, col = wn*64 + j*16 + (lane&15)
    #pragma unroll
    for (int i = 0; i < 8; ++i) {
        const size_t row_base = brow + wm * 128 + i * 16 + (lane >> 4) * 4;
        #pragma unroll
        for (int j = 0; j < 4; ++j) {
            const size_t col = bcol + wn * 64 + j * 16 + lr;
            const float bv = bias[col];
            #pragma unroll
            for (int jj = 0; jj < 4; ++jj)
                C[(row_base + jj) * (size_t)N_DIM + col] = acc[i][j][jj] + bv;
        }
    }
}

extern "C" void kernel_launch(void* const* d_in, const int* in_sizes, int n_in,
                              void* d_out, int out_size, void* d_ws, size_t ws_size,
                              hipStream_t stream) {
    const float* x = (const float*)d_in[0];
    const float* w = (const float*)d_in[1];
    const float* bias = (const float*)d_in[2];
    float* out = (float*)d_out;

    unsigned short* xq = (unsigned short*)d_ws;
    unsigned short* wq = xq + (size_t)M_DIM * K_DIM;

    quant_x<<<(M_DIM * (K_DIM / 128)) / 8, 256, 0, stream>>>(x, xq);
    quant_w<<<(N_DIM / 128) * (K_DIM / 128), 256, 0, stream>>>(w, wq);
    gemm256<<<(M_DIM / 256) * (N_DIM / 256), 512, 0, stream>>>(xq, wq, bias, out);
}